// Round 1
// baseline (26863.663 us; speedup 1.0000x reference)
//
#include <hip/hip_runtime.h>

#define T_STEPS 4096
#define HID     512
#define NCH     256
#define DIM     128
#define VOCAB   32000
#define GRU_WGS 32

// ============================ GRU ============================
// 32 WGs x 256 threads. wave-level producer units; 16-lane teams per output j.
// h exchange via tagged u64 slots: hi32 = step tag, lo32 = float bits.
__global__ __launch_bounds__(256) void gru_kernel(
    const float* __restrict__ x,
    const float* __restrict__ w_ih,
    const float* __restrict__ w_hh,
    const float* __restrict__ b_ih,
    const float* __restrict__ b_hh,
    unsigned long long* hg,            // 2 * 512 tagged slots (zeroed each launch)
    float* __restrict__ evolved)       // (4096, 512)
{
  const int tid  = threadIdx.x;
  const int wave = tid >> 6;
  const int lane = tid & 63;
  const int team = lane >> 4;          // 0..3
  const int p    = lane & 15;          // k-slice index within team
  const int j    = blockIdx.x * 16 + wave * 4 + team;   // 0..511
  const int k0   = p * 32;

  // weights for rows j (r-gate), 512+j (z-gate), 1024+j (n-gate), cols [k0,k0+32)
  float4 w[3][8];
#pragma unroll
  for (int d = 0; d < 3; ++d) {
    const float4* wr = reinterpret_cast<const float4*>(w_hh + (size_t)(d * HID + j) * HID + k0);
#pragma unroll
    for (int q = 0; q < 8; ++q) w[d][q] = wr[q];
  }
  // xp_t = xs[t]*c + b_ih  (quat input is rank-1 in the scales vector)
  float c3[3], bi3[3], bh3[3];
#pragma unroll
  for (int d = 0; d < 3; ++d) {
    int r = d * HID + j;
    c3[d]  = w_ih[r*4+0] + 0.1f*w_ih[r*4+1] + 0.01f*w_ih[r*4+2] + 0.001f*w_ih[r*4+3];
    bi3[d] = b_ih[r];
    bh3[d] = b_hh[r];
  }

  float hprev = 0.0f;  // leader lanes (p==0) carry h[j]
  for (int s = 1; s <= T_STEPS; ++s) {
    const int rb = (s - 1) & 1;
    const int wb = s & 1;
    const unsigned int want = (unsigned int)(s - 1);
    unsigned long long* rs = hg + rb * HID + k0;

    const float xt = x[s - 1];   // off critical path: issue before poll

    float h[32];
    for (;;) {
      unsigned long long v[32];
#pragma unroll
      for (int q = 0; q < 32; ++q)
        v[q] = __hip_atomic_load(rs + q, __ATOMIC_RELAXED, __HIP_MEMORY_SCOPE_AGENT);
      bool ok = true;
#pragma unroll
      for (int q = 0; q < 32; ++q) ok &= ((unsigned int)(v[q] >> 32) == want);
      if (ok) {
#pragma unroll
        for (int q = 0; q < 32; ++q) h[q] = __uint_as_float((unsigned int)v[q]);
        break;
      }
      __builtin_amdgcn_s_sleep(2);
    }

    float a0 = 0.f, a1 = 0.f, a2 = 0.f;
#pragma unroll
    for (int q = 0; q < 8; ++q) {
      a0 = fmaf(w[0][q].x, h[4*q+0], a0);
      a0 = fmaf(w[0][q].y, h[4*q+1], a0);
      a0 = fmaf(w[0][q].z, h[4*q+2], a0);
      a0 = fmaf(w[0][q].w, h[4*q+3], a0);
      a1 = fmaf(w[1][q].x, h[4*q+0], a1);
      a1 = fmaf(w[1][q].y, h[4*q+1], a1);
      a1 = fmaf(w[1][q].z, h[4*q+2], a1);
      a1 = fmaf(w[1][q].w, h[4*q+3], a1);
      a2 = fmaf(w[2][q].x, h[4*q+0], a2);
      a2 = fmaf(w[2][q].y, h[4*q+1], a2);
      a2 = fmaf(w[2][q].z, h[4*q+2], a2);
      a2 = fmaf(w[2][q].w, h[4*q+3], a2);
    }
    // butterfly reduce within the 16-lane team
#pragma unroll
    for (int m = 8; m >= 1; m >>= 1) {
      a0 += __shfl_xor(a0, m);
      a1 += __shfl_xor(a1, m);
      a2 += __shfl_xor(a2, m);
    }

    if (p == 0) {
      const float rg = 1.0f / (1.0f + expf(-(fmaf(xt, c3[0], bi3[0]) + a0 + bh3[0])));
      const float zg = 1.0f / (1.0f + expf(-(fmaf(xt, c3[1], bi3[1]) + a1 + bh3[1])));
      const float ng = tanhf(fmaf(xt, c3[2], bi3[2]) + rg * (a2 + bh3[2]));
      const float hn = (1.0f - zg) * ng + zg * hprev;
      hprev = hn;
      const unsigned long long pk =
          ((unsigned long long)(unsigned int)s << 32) | (unsigned long long)__float_as_uint(hn);
      __hip_atomic_store(hg + wb * HID + j, pk, __ATOMIC_RELAXED, __HIP_MEMORY_SCOPE_AGENT);
      evolved[(size_t)(s - 1) * HID + j] = hn;
    }
  }
}

// ==================== FFT -> phase filter -> IFFT ====================
__device__ __forceinline__ void fft4096(float2* buf, int tid)
{
  for (int st = 0; st < 12; ++st) {
    const int half = 1 << st;
    const int len  = 2 << st;
    const float ang0 = -6.283185307179586f / (float)len;
    for (int i = tid; i < 2048; i += 256) {
      const int blk = i >> st;
      const int pos = i & (half - 1);
      const int idx = blk * len + pos;
      float sn, cs;
      sincosf(ang0 * (float)pos, &sn, &cs);
      const float2 u = buf[idx];
      const float2 v = buf[idx + half];
      const float tr = v.x * cs - v.y * sn;
      const float ti = v.x * sn + v.y * cs;
      buf[idx]        = make_float2(u.x + tr, u.y + ti);
      buf[idx + half] = make_float2(u.x - tr, u.y - ti);
    }
    __syncthreads();
  }
}

__global__ __launch_bounds__(256) void fft_kernel(
    const float* __restrict__ evolved,   // (4096, 512)
    const float* __restrict__ alpha_p,
    float* __restrict__ ft)              // (4096, 256)
{
  __shared__ float2 buf[4096];           // 32 KB
  const int tid = threadIdx.x;
  const int c = blockIdx.x;
  const float alpha = alpha_p[0];

  // load channel with bit-reversal; real = ch 2c, imag = ch 2c+1
  for (int t = tid; t < 4096; t += 256) {
    const int r = __brev((unsigned)t) >> 20;
    buf[r] = make_float2(evolved[(size_t)t * HID + 2 * c],
                         evolved[(size_t)t * HID + 2 * c + 1]);
  }
  __syncthreads();
  fft4096(buf, tid);

  // phase filter, then conjugate (inverse via conj-fft)
  for (int t = tid; t < 4096; t += 256) {
    float2 v = buf[t];
    const float km = sqrtf(v.x * v.x + v.y * v.y) + 1e-10f;
    const float pf = alpha * atanf(logf(km));
    float sn, cs;
    sincosf(pf, &sn, &cs);
    const float rr = v.x * cs - v.y * sn;
    const float ii = v.x * sn + v.y * cs;
    buf[t] = make_float2(rr, -ii);
  }
  __syncthreads();
  // bit-reverse permute in place (disjoint pair swaps)
  for (int t = tid; t < 4096; t += 256) {
    const int r = __brev((unsigned)t) >> 20;
    if (r > t) { float2 tmp = buf[t]; buf[t] = buf[r]; buf[r] = tmp; }
  }
  __syncthreads();
  fft4096(buf, tid);

  const float inv = 1.0f / 4096.0f;
  for (int t = tid; t < 4096; t += 256) {
    ft[(size_t)t * NCH + c] = buf[t].x * inv;   // Re(ifft) = Re(fft(conj))/N
  }
}

// ==================== coh = ft @ pc_w.T + pc_b ====================
__global__ __launch_bounds__(256) void coh_kernel(
    const float* __restrict__ ft,     // (4096, 256)
    const float* __restrict__ pcw,    // (128, 256)
    const float* __restrict__ pcb,    // (128)
    float* __restrict__ x0)           // (4096, 128)
{
  __shared__ float wT[64][132];       // [k][col], padded
  __shared__ float fT[64][68];        // [k][row], padded
  const int tid = threadIdx.x;
  const int rg = tid >> 4;            // rows rg*4 .. +4
  const int cg = tid & 15;            // cols cg*8 .. +8
  const int t0 = blockIdx.x * 64;
  float acc[4][8];
#pragma unroll
  for (int i = 0; i < 4; ++i)
#pragma unroll
    for (int jj = 0; jj < 8; ++jj) acc[i][jj] = 0.f;

  for (int kt = 0; kt < 256; kt += 64) {
    __syncthreads();
    for (int u = tid; u < 64 * DIM; u += 256) {
      const int col = u >> 6, kk = u & 63;
      wT[kk][col] = pcw[col * 256 + kt + kk];
    }
    for (int u = tid; u < 64 * 64; u += 256) {
      const int row = u >> 6, kk = u & 63;
      fT[kk][row] = ft[(size_t)(t0 + row) * NCH + kt + kk];
    }
    __syncthreads();
#pragma unroll 4
    for (int k = 0; k < 64; ++k) {
      const float4 a  = *(const float4*)&fT[k][rg * 4];
      const float4 w0 = *(const float4*)&wT[k][cg * 8];
      const float4 w1 = *(const float4*)&wT[k][cg * 8 + 4];
      const float av[4] = {a.x, a.y, a.z, a.w};
      const float wv[8] = {w0.x, w0.y, w0.z, w0.w, w1.x, w1.y, w1.z, w1.w};
#pragma unroll
      for (int i = 0; i < 4; ++i)
#pragma unroll
        for (int jj = 0; jj < 8; ++jj)
          acc[i][jj] = fmaf(av[i], wv[jj], acc[i][jj]);
    }
  }
#pragma unroll
  for (int i = 0; i < 4; ++i) {
    const int t = t0 + rg * 4 + i;
#pragma unroll
    for (int jj = 0; jj < 8; ++jj)
      x0[(size_t)t * DIM + cg * 8 + jj] = acc[i][jj] + pcb[cg * 8 + jj];
  }
}

// ==================== logits = (x0@Pre.T)^2 + (x0@Pim.T)^2 ====================
__global__ __launch_bounds__(256) void logits_kernel(
    const float* __restrict__ x0,      // (4096, 128)
    const float* __restrict__ patre,   // (32000, 128)
    const float* __restrict__ patim,   // (32000, 128)
    float* __restrict__ out)           // (4096, 32000)
{
  __shared__ float aT[32][68];         // [k][m], BM=64
  __shared__ float brT[32][132];       // [k][n], BN=128
  __shared__ float biT[32][132];
  const int tid = threadIdx.x;
  const int tx = tid & 31;             // cols tx*4 .. +4
  const int ty = tid >> 5;             // rows ty*8 .. +8
  const int m0 = blockIdx.y * 64;
  const int n0 = blockIdx.x * 128;
  float accr[8][4], acci[8][4];
#pragma unroll
  for (int i = 0; i < 8; ++i)
#pragma unroll
    for (int jj = 0; jj < 4; ++jj) { accr[i][jj] = 0.f; acci[i][jj] = 0.f; }

  for (int kt = 0; kt < 128; kt += 32) {
    __syncthreads();
    for (int u = tid; u < 64 * 32; u += 256) {
      const int mm = u >> 5, kk = u & 31;
      aT[kk][mm] = x0[(size_t)(m0 + mm) * DIM + kt + kk];
    }
    for (int u = tid; u < 128 * 32; u += 256) {
      const int nn = u >> 5, kk = u & 31;
      brT[kk][nn] = patre[(size_t)(n0 + nn) * DIM + kt + kk];
      biT[kk][nn] = patim[(size_t)(n0 + nn) * DIM + kt + kk];
    }
    __syncthreads();
#pragma unroll 4
    for (int k = 0; k < 32; ++k) {
      const float4 q0 = *(const float4*)&aT[k][ty * 8];
      const float4 q1 = *(const float4*)&aT[k][ty * 8 + 4];
      const float4 br = *(const float4*)&brT[k][tx * 4];
      const float4 bi = *(const float4*)&biT[k][tx * 4];
      const float av[8]  = {q0.x, q0.y, q0.z, q0.w, q1.x, q1.y, q1.z, q1.w};
      const float brv[4] = {br.x, br.y, br.z, br.w};
      const float biv[4] = {bi.x, bi.y, bi.z, bi.w};
#pragma unroll
      for (int i = 0; i < 8; ++i)
#pragma unroll
        for (int jj = 0; jj < 4; ++jj) {
          accr[i][jj] = fmaf(av[i], brv[jj], accr[i][jj]);
          acci[i][jj] = fmaf(av[i], biv[jj], acci[i][jj]);
        }
    }
  }
#pragma unroll
  for (int i = 0; i < 8; ++i) {
    const size_t m = (size_t)(m0 + ty * 8 + i);
    float4 o;
    o.x = accr[i][0] * accr[i][0] + acci[i][0] * acci[i][0];
    o.y = accr[i][1] * accr[i][1] + acci[i][1] * acci[i][1];
    o.z = accr[i][2] * accr[i][2] + acci[i][2] * acci[i][2];
    o.w = accr[i][3] * accr[i][3] + acci[i][3] * acci[i][3];
    *(float4*)&out[m * VOCAB + n0 + tx * 4] = o;
  }
}

// ============================ launch ============================
extern "C" void kernel_launch(void* const* d_in, const int* in_sizes, int n_in,
                              void* d_out, int out_size, void* d_ws, size_t ws_size,
                              hipStream_t stream)
{
  const float* x     = (const float*)d_in[0];
  const float* w_ih  = (const float*)d_in[1];
  const float* w_hh  = (const float*)d_in[2];
  const float* b_ih  = (const float*)d_in[3];
  const float* b_hh  = (const float*)d_in[4];
  const float* alpha = (const float*)d_in[5];
  const float* pc_w  = (const float*)d_in[6];
  const float* pc_b  = (const float*)d_in[7];
  const float* patre = (const float*)d_in[8];
  const float* patim = (const float*)d_in[9];

  float* out = (float*)d_out;
  // Intermediates parked inside d_out (524 MB): the final kernel reads only x0
  // (in d_ws) and overwrites all of d_out afterwards.
  float* evolved = out;                 // 4096*512  = 2,097,152 floats
  float* ft      = out + 4194304;       // 4096*256  = 1,048,576 floats

  unsigned long long* hg = (unsigned long long*)d_ws;   // 2*512 slots = 8 KB
  float* x0 = (float*)((char*)d_ws + 8192);             // 4096*128 = 2 MB

  // Reset tagged slots every launch (tag 0 == h0 == 0); replay-safe.
  hipMemsetAsync(d_ws, 0, 8192, stream);

  gru_kernel<<<GRU_WGS, 256, 0, stream>>>(x, w_ih, w_hh, b_ih, b_hh, hg, evolved);
  fft_kernel<<<256, 256, 0, stream>>>(evolved, alpha, ft);
  coh_kernel<<<64, 256, 0, stream>>>(ft, pc_w, pc_b, x0);
  logits_kernel<<<dim3(250, 64), 256, 0, stream>>>(x0, patre, patim, out);
}

// Round 2
// 11562.341 us; speedup vs baseline: 2.3234x; 2.3234x over previous
//
#include <hip/hip_runtime.h>

#define T_STEPS 4096
#define HID     512
#define NCH     256
#define DIM     128
#define VOCAB   32000
#define GRU_WGS 32

// ============================ GRU ============================
// 32 WGs x 256 threads. 16-lane teams per output j; WG-cooperative polling:
// 256 threads poll 2 tagged slots each, gate on __syncthreads_and, deposit to
// LDS, then every lane reads its 32-wide k-slice from LDS (rotated by p&7 so
// ds_read_b128 is 2-way-conflict-free; weights loaded in the same rotated
// order so all register indices stay compile-time).
// h exchange via tagged u64 slots: hi32 = step tag, lo32 = float bits.
__global__ __launch_bounds__(256) void gru_kernel(
    const float* __restrict__ x,
    const float* __restrict__ w_ih,
    const float* __restrict__ w_hh,
    const float* __restrict__ b_ih,
    const float* __restrict__ b_hh,
    unsigned long long* hg,            // 2 * 512 tagged slots (zeroed each launch)
    float* __restrict__ evolved)       // (4096, 512)
{
  __shared__ float hs[HID];
  const int tid  = threadIdx.x;
  const int wave = tid >> 6;
  const int lane = tid & 63;
  const int team = lane >> 4;          // 0..3
  const int p    = lane & 15;          // k-slice index within team
  const int pr   = p & 7;              // bank-rotation amount
  const int j    = blockIdx.x * 16 + wave * 4 + team;   // 0..511
  const int k0   = p * 32;

  // weights for rows j (r), 512+j (z), 1024+j (n), cols [k0,k0+32), rotated:
  // w[d][qq] holds float4 at column k0 + 4*((qq+pr)&7).
  float4 w[3][8];
#pragma unroll
  for (int d = 0; d < 3; ++d) {
    const float4* wr = reinterpret_cast<const float4*>(w_hh + (size_t)(d * HID + j) * HID);
#pragma unroll
    for (int qq = 0; qq < 8; ++qq) {
      const int r = (qq + pr) & 7;
      w[d][qq] = wr[p * 8 + r];
    }
  }
  // xp_t = xs[t]*c + b_ih  (quat input is rank-1 in the scales vector)
  float c3[3], bi3[3], bh3[3];
#pragma unroll
  for (int d = 0; d < 3; ++d) {
    int r = d * HID + j;
    c3[d]  = w_ih[r*4+0] + 0.1f*w_ih[r*4+1] + 0.01f*w_ih[r*4+2] + 0.001f*w_ih[r*4+3];
    bi3[d] = b_ih[r];
    bh3[d] = b_hh[r];
  }

  float hprev = 0.0f;  // leader lanes (p==0) carry h[j]
  for (int s = 1; s <= T_STEPS; ++s) {
    const int rb = (s - 1) & 1;
    const int wb = s & 1;
    const unsigned int want = (unsigned int)(s - 1);
    const unsigned long long* rs = hg + rb * HID;

    const float xt = x[s - 1];   // uniform scalar load, off critical path

    // ---- WG-cooperative poll: 2 slots per thread ----
    unsigned long long vA, vB;
    for (;;) {
      vA = __hip_atomic_load(rs + 2 * tid,     __ATOMIC_RELAXED, __HIP_MEMORY_SCOPE_AGENT);
      vB = __hip_atomic_load(rs + 2 * tid + 1, __ATOMIC_RELAXED, __HIP_MEMORY_SCOPE_AGENT);
      const bool ok = ((unsigned int)(vA >> 32) == want) &
                      ((unsigned int)(vB >> 32) == want);
      if (__syncthreads_and(ok)) break;
    }
    hs[2 * tid]     = __uint_as_float((unsigned int)vA);
    hs[2 * tid + 1] = __uint_as_float((unsigned int)vB);
    __syncthreads();

    // ---- dot products from LDS (rotated order; sum is order-invariant) ----
    float a0 = 0.f, a1 = 0.f, a2 = 0.f;
#pragma unroll
    for (int qq = 0; qq < 8; ++qq) {
      const int r = (qq + pr) & 7;
      const float4 h4 = *reinterpret_cast<const float4*>(&hs[k0 + 4 * r]);
      a0 = fmaf(w[0][qq].x, h4.x, a0);
      a0 = fmaf(w[0][qq].y, h4.y, a0);
      a0 = fmaf(w[0][qq].z, h4.z, a0);
      a0 = fmaf(w[0][qq].w, h4.w, a0);
      a1 = fmaf(w[1][qq].x, h4.x, a1);
      a1 = fmaf(w[1][qq].y, h4.y, a1);
      a1 = fmaf(w[1][qq].z, h4.z, a1);
      a1 = fmaf(w[1][qq].w, h4.w, a1);
      a2 = fmaf(w[2][qq].x, h4.x, a2);
      a2 = fmaf(w[2][qq].y, h4.y, a2);
      a2 = fmaf(w[2][qq].z, h4.z, a2);
      a2 = fmaf(w[2][qq].w, h4.w, a2);
    }
    // butterfly reduce within the 16-lane team
#pragma unroll
    for (int m = 8; m >= 1; m >>= 1) {
      a0 += __shfl_xor(a0, m);
      a1 += __shfl_xor(a1, m);
      a2 += __shfl_xor(a2, m);
    }

    if (p == 0) {
      const float rg = 1.0f / (1.0f + expf(-(fmaf(xt, c3[0], bi3[0]) + a0 + bh3[0])));
      const float zg = 1.0f / (1.0f + expf(-(fmaf(xt, c3[1], bi3[1]) + a1 + bh3[1])));
      const float ng = tanhf(fmaf(xt, c3[2], bi3[2]) + rg * (a2 + bh3[2]));
      const float hn = (1.0f - zg) * ng + zg * hprev;
      hprev = hn;
      const unsigned long long pk =
          ((unsigned long long)(unsigned int)s << 32) | (unsigned long long)__float_as_uint(hn);
      __hip_atomic_store(hg + wb * HID + j, pk, __ATOMIC_RELAXED, __HIP_MEMORY_SCOPE_AGENT);
      evolved[(size_t)(s - 1) * HID + j] = hn;
    }
  }
}

// ==================== FFT -> phase filter -> IFFT ====================
__device__ __forceinline__ void fft4096(float2* buf, int tid)
{
  for (int st = 0; st < 12; ++st) {
    const int half = 1 << st;
    const int len  = 2 << st;
    const float ang0 = -6.283185307179586f / (float)len;
    for (int i = tid; i < 2048; i += 256) {
      const int blk = i >> st;
      const int pos = i & (half - 1);
      const int idx = blk * len + pos;
      float sn, cs;
      sincosf(ang0 * (float)pos, &sn, &cs);
      const float2 u = buf[idx];
      const float2 v = buf[idx + half];
      const float tr = v.x * cs - v.y * sn;
      const float ti = v.x * sn + v.y * cs;
      buf[idx]        = make_float2(u.x + tr, u.y + ti);
      buf[idx + half] = make_float2(u.x - tr, u.y - ti);
    }
    __syncthreads();
  }
}

__global__ __launch_bounds__(256) void fft_kernel(
    const float* __restrict__ evolved,   // (4096, 512)
    const float* __restrict__ alpha_p,
    float* __restrict__ ft)              // (4096, 256)
{
  __shared__ float2 buf[4096];           // 32 KB
  const int tid = threadIdx.x;
  const int c = blockIdx.x;
  const float alpha = alpha_p[0];

  // load channel with bit-reversal; real = ch 2c, imag = ch 2c+1
  for (int t = tid; t < 4096; t += 256) {
    const int r = __brev((unsigned)t) >> 20;
    buf[r] = make_float2(evolved[(size_t)t * HID + 2 * c],
                         evolved[(size_t)t * HID + 2 * c + 1]);
  }
  __syncthreads();
  fft4096(buf, tid);

  // phase filter, then conjugate (inverse via conj-fft)
  for (int t = tid; t < 4096; t += 256) {
    float2 v = buf[t];
    const float km = sqrtf(v.x * v.x + v.y * v.y) + 1e-10f;
    const float pf = alpha * atanf(logf(km));
    float sn, cs;
    sincosf(pf, &sn, &cs);
    const float rr = v.x * cs - v.y * sn;
    const float ii = v.x * sn + v.y * cs;
    buf[t] = make_float2(rr, -ii);
  }
  __syncthreads();
  // bit-reverse permute in place (disjoint pair swaps)
  for (int t = tid; t < 4096; t += 256) {
    const int r = __brev((unsigned)t) >> 20;
    if (r > t) { float2 tmp = buf[t]; buf[t] = buf[r]; buf[r] = tmp; }
  }
  __syncthreads();
  fft4096(buf, tid);

  const float inv = 1.0f / 4096.0f;
  for (int t = tid; t < 4096; t += 256) {
    ft[(size_t)t * NCH + c] = buf[t].x * inv;   // Re(ifft) = Re(fft(conj))/N
  }
}

// ==================== coh = ft @ pc_w.T + pc_b ====================
__global__ __launch_bounds__(256) void coh_kernel(
    const float* __restrict__ ft,     // (4096, 256)
    const float* __restrict__ pcw,    // (128, 256)
    const float* __restrict__ pcb,    // (128)
    float* __restrict__ x0)           // (4096, 128)
{
  __shared__ float wT[64][132];       // [k][col], padded
  __shared__ float fT[64][68];        // [k][row], padded
  const int tid = threadIdx.x;
  const int rg = tid >> 4;            // rows rg*4 .. +4
  const int cg = tid & 15;            // cols cg*8 .. +8
  const int t0 = blockIdx.x * 64;
  float acc[4][8];
#pragma unroll
  for (int i = 0; i < 4; ++i)
#pragma unroll
    for (int jj = 0; jj < 8; ++jj) acc[i][jj] = 0.f;

  for (int kt = 0; kt < 256; kt += 64) {
    __syncthreads();
    for (int u = tid; u < 64 * DIM; u += 256) {
      const int col = u >> 6, kk = u & 63;
      wT[kk][col] = pcw[col * 256 + kt + kk];
    }
    for (int u = tid; u < 64 * 64; u += 256) {
      const int row = u >> 6, kk = u & 63;
      fT[kk][row] = ft[(size_t)(t0 + row) * NCH + kt + kk];
    }
    __syncthreads();
#pragma unroll 4
    for (int k = 0; k < 64; ++k) {
      const float4 a  = *(const float4*)&fT[k][rg * 4];
      const float4 w0 = *(const float4*)&wT[k][cg * 8];
      const float4 w1 = *(const float4*)&wT[k][cg * 8 + 4];
      const float av[4] = {a.x, a.y, a.z, a.w};
      const float wv[8] = {w0.x, w0.y, w0.z, w0.w, w1.x, w1.y, w1.z, w1.w};
#pragma unroll
      for (int i = 0; i < 4; ++i)
#pragma unroll
        for (int jj = 0; jj < 8; ++jj)
          acc[i][jj] = fmaf(av[i], wv[jj], acc[i][jj]);
    }
  }
#pragma unroll
  for (int i = 0; i < 4; ++i) {
    const int t = t0 + rg * 4 + i;
#pragma unroll
    for (int jj = 0; jj < 8; ++jj)
      x0[(size_t)t * DIM + cg * 8 + jj] = acc[i][jj] + pcb[cg * 8 + jj];
  }
}

// ==================== logits = (x0@Pre.T)^2 + (x0@Pim.T)^2 ====================
__global__ __launch_bounds__(256) void logits_kernel(
    const float* __restrict__ x0,      // (4096, 128)
    const float* __restrict__ patre,   // (32000, 128)
    const float* __restrict__ patim,   // (32000, 128)
    float* __restrict__ out)           // (4096, 32000)
{
  __shared__ float aT[32][68];         // [k][m], BM=64
  __shared__ float brT[32][132];       // [k][n], BN=128
  __shared__ float biT[32][132];
  const int tid = threadIdx.x;
  const int tx = tid & 31;             // cols tx*4 .. +4
  const int ty = tid >> 5;             // rows ty*8 .. +8
  const int m0 = blockIdx.y * 64;
  const int n0 = blockIdx.x * 128;
  float accr[8][4], acci[8][4];
#pragma unroll
  for (int i = 0; i < 8; ++i)
#pragma unroll
    for (int jj = 0; jj < 4; ++jj) { accr[i][jj] = 0.f; acci[i][jj] = 0.f; }

  for (int kt = 0; kt < 128; kt += 32) {
    __syncthreads();
    for (int u = tid; u < 64 * 32; u += 256) {
      const int mm = u >> 5, kk = u & 31;
      aT[kk][mm] = x0[(size_t)(m0 + mm) * DIM + kt + kk];
    }
    for (int u = tid; u < 128 * 32; u += 256) {
      const int nn = u >> 5, kk = u & 31;
      brT[kk][nn] = patre[(size_t)(n0 + nn) * DIM + kt + kk];
      biT[kk][nn] = patim[(size_t)(n0 + nn) * DIM + kt + kk];
    }
    __syncthreads();
#pragma unroll 4
    for (int k = 0; k < 32; ++k) {
      const float4 q0 = *(const float4*)&aT[k][ty * 8];
      const float4 q1 = *(const float4*)&aT[k][ty * 8 + 4];
      const float4 br = *(const float4*)&brT[k][tx * 4];
      const float4 bi = *(const float4*)&biT[k][tx * 4];
      const float av[8]  = {q0.x, q0.y, q0.z, q0.w, q1.x, q1.y, q1.z, q1.w};
      const float brv[4] = {br.x, br.y, br.z, br.w};
      const float biv[4] = {bi.x, bi.y, bi.z, bi.w};
#pragma unroll
      for (int i = 0; i < 8; ++i)
#pragma unroll
        for (int jj = 0; jj < 4; ++jj) {
          accr[i][jj] = fmaf(av[i], brv[jj], accr[i][jj]);
          acci[i][jj] = fmaf(av[i], biv[jj], acci[i][jj]);
        }
    }
  }
#pragma unroll
  for (int i = 0; i < 8; ++i) {
    const size_t m = (size_t)(m0 + ty * 8 + i);
    float4 o;
    o.x = accr[i][0] * accr[i][0] + acci[i][0] * acci[i][0];
    o.y = accr[i][1] * accr[i][1] + acci[i][1] * acci[i][1];
    o.z = accr[i][2] * accr[i][2] + acci[i][2] * acci[i][2];
    o.w = accr[i][3] * accr[i][3] + acci[i][3] * acci[i][3];
    *(float4*)&out[m * VOCAB + n0 + tx * 4] = o;
  }
}

// ============================ launch ============================
extern "C" void kernel_launch(void* const* d_in, const int* in_sizes, int n_in,
                              void* d_out, int out_size, void* d_ws, size_t ws_size,
                              hipStream_t stream)
{
  const float* x     = (const float*)d_in[0];
  const float* w_ih  = (const float*)d_in[1];
  const float* w_hh  = (const float*)d_in[2];
  const float* b_ih  = (const float*)d_in[3];
  const float* b_hh  = (const float*)d_in[4];
  const float* alpha = (const float*)d_in[5];
  const float* pc_w  = (const float*)d_in[6];
  const float* pc_b  = (const float*)d_in[7];
  const float* patre = (const float*)d_in[8];
  const float* patim = (const float*)d_in[9];

  float* out = (float*)d_out;
  // Intermediates parked inside d_out (524 MB): the final kernel reads only x0
  // (in d_ws) and overwrites all of d_out afterwards.
  float* evolved = out;                 // 4096*512  = 2,097,152 floats
  float* ft      = out + 4194304;       // 4096*256  = 1,048,576 floats

  unsigned long long* hg = (unsigned long long*)d_ws;   // 2*512 slots = 8 KB
  float* x0 = (float*)((char*)d_ws + 8192);             // 4096*128 = 2 MB

  // Reset tagged slots every launch (tag 0 == h0 == 0); replay-safe.
  hipMemsetAsync(d_ws, 0, 8192, stream);

  gru_kernel<<<GRU_WGS, 256, 0, stream>>>(x, w_ih, w_hh, b_ih, b_hh, hg, evolved);
  fft_kernel<<<256, 256, 0, stream>>>(evolved, alpha, ft);
  coh_kernel<<<64, 256, 0, stream>>>(ft, pc_w, pc_b, x0);
  logits_kernel<<<dim3(250, 64), 256, 0, stream>>>(x0, patre, patim, out);
}